// Round 3
// baseline (754.555 us; speedup 1.0000x reference)
//
#include <hip/hip_runtime.h>

#define Cdim 128
#define Hdim 1024
#define Idim 512
#define Odim 128
#define HT 256
#define HS_LD 264   // shorts; 528 B/row = 132 dwords -> stride 4 banks, 2-way (free)

typedef __attribute__((ext_vector_type(8))) short short8;
typedef __attribute__((ext_vector_type(4))) float f32x4;

__device__ __forceinline__ short8 cvt8(float4 lo, float4 hi) {
    // pack 8 fp32 -> 8 bf16 (truncate) via byte-perm
    unsigned int p0 = __builtin_amdgcn_perm(__float_as_uint(lo.y), __float_as_uint(lo.x), 0x07060302);
    unsigned int p1 = __builtin_amdgcn_perm(__float_as_uint(lo.w), __float_as_uint(lo.z), 0x07060302);
    unsigned int p2 = __builtin_amdgcn_perm(__float_as_uint(hi.y), __float_as_uint(hi.x), 0x07060302);
    unsigned int p3 = __builtin_amdgcn_perm(__float_as_uint(hi.w), __float_as_uint(hi.z), 0x07060302);
    union { uint4 u; short8 s; } r;
    r.u = make_uint4(p0, p1, p2, p3);
    return r.s;
}

// 512 threads (8 waves): wm = wave&1 (M half of 64), wn = wave>>1 (N quarter).
// Barrier-free K-loops: A/B MFMA fragments are contiguous-in-K slices of
// row-major global arrays -> per-lane 2x dwordx4 + in-reg cvt, no staging LDS.
// LDS only for the h C-layout -> A-layout transpose (Hs).
__global__ __launch_bounds__(512, 4) void mlp_fused2(
    const float* __restrict__ x, const float* __restrict__ w1,
    const float* __restrict__ b1, const float* __restrict__ w2,
    const float* __restrict__ b2, float* __restrict__ out)
{
    __shared__ unsigned short Hs[64 * HS_LD];   // 33792 B

    const int t    = threadIdx.x;
    const int lane = t & 63;
    const int q    = lane >> 4;
    const int r16  = lane & 15;
    const int wave = t >> 6;
    const int wm   = wave & 1;    // M: wm*32
    const int wn   = wave >> 1;   // 0..3: layer1 N: wn*64, layer2 N: wn*32

    // XCD swizzle: 8 b-blocks of channel c (and the 16 channels of one out-line
    // group) share an XCD -> w1[c] re-reads stay in that XCD's L2.
    const int bid  = blockIdx.x;
    const int g    = bid & 7;
    const int s    = bid >> 3;          // 0..63
    const int c    = g * 16 + (s & 15);
    const int row0 = (s >> 4) * 64;     // 4 b-tiles of 64

    // per-lane base pointers (k-offset q*8 folded in)
    const float* pa[2];
    #pragma unroll
    for (int i = 0; i < 2; ++i)
        pa[i] = x + (size_t)(row0 + wm * 32 + i * 16 + r16) * (Cdim * Idim)
                  + (size_t)c * Idim + q * 8;
    const float* pb1[4];
    #pragma unroll
    for (int j = 0; j < 4; ++j)
        pb1[j] = w1 + (size_t)c * (Hdim * Idim)
                    + (size_t)(wn * 64 + j * 16 + r16) * Idim + q * 8;
    const float* pb2[2];
    #pragma unroll
    for (int j = 0; j < 2; ++j)
        pb2[j] = w2 + (size_t)c * (Odim * Hdim)
                    + (size_t)(wn * 32 + j * 16 + r16) * Hdim + q * 8;

    // persistent layer-2 accumulators, init with b2 (n depends only on j,r16)
    f32x4 acc2[2][2];
    #pragma unroll
    for (int j = 0; j < 2; ++j) {
        float bv = b2[c * Odim + wn * 32 + j * 16 + r16];
        f32x4 z = {bv, bv, bv, bv};
        acc2[0][j] = z;
        acc2[1][j] = z;
    }

    for (int ht = 0; ht < Hdim / HT; ++ht) {
        f32x4 acc1[2][4];
        {
            f32x4 z = {0.f, 0.f, 0.f, 0.f};
            #pragma unroll
            for (int i = 0; i < 2; ++i)
                #pragma unroll
                for (int j = 0; j < 4; ++j) acc1[i][j] = z;
        }

        // ---- layer 1: acc1 (64x256 tile) += x (64x512) * w1_slice^T ----
        const size_t htoff = (size_t)ht * (HT * Idim);
        #pragma unroll 4
        for (int ks = 0; ks < Idim / 32; ++ks) {
            const int k0 = ks * 32;
            short8 a8[2], b8[4];
            #pragma unroll
            for (int i = 0; i < 2; ++i) {
                const float* p = pa[i] + k0;
                a8[i] = cvt8(*(const float4*)p, *(const float4*)(p + 4));
            }
            #pragma unroll
            for (int j = 0; j < 4; ++j) {
                const float* p = pb1[j] + htoff + k0;
                b8[j] = cvt8(*(const float4*)p, *(const float4*)(p + 4));
            }
            #pragma unroll
            for (int i = 0; i < 2; ++i)
                #pragma unroll
                for (int j = 0; j < 4; ++j)
                    acc1[i][j] = __builtin_amdgcn_mfma_f32_16x16x32_bf16(a8[i], b8[j], acc1[i][j], 0, 0, 0);
        }

        __syncthreads();   // prev-ht layer-2 Hs reads complete before overwrite
        // ---- epilogue: Hs = bf16(relu(acc1 + b1)), C-layout -> [m][n] ----
        #pragma unroll
        for (int j = 0; j < 4; ++j) {
            const int n = wn * 64 + j * 16 + r16;
            const float b1v = b1[c * Hdim + ht * HT + n];
            #pragma unroll
            for (int i = 0; i < 2; ++i)
                #pragma unroll
                for (int r = 0; r < 4; ++r) {
                    const int m = wm * 32 + i * 16 + q * 4 + r;
                    float hv = fmaxf(acc1[i][j][r] + b1v, 0.f);
                    Hs[m * HS_LD + n] = (unsigned short)(__float_as_uint(hv) >> 16);
                }
        }
        __syncthreads();

        // ---- layer 2 partial: acc2 += Hs (64xHT) * w2_slice^T ----
        #pragma unroll 2
        for (int ks = 0; ks < HT / 32; ++ks) {
            const int k0 = ks * 32;
            short8 a8[2], b8[2];
            #pragma unroll
            for (int i = 0; i < 2; ++i)
                a8[i] = *(const short8*)&Hs[(wm * 32 + i * 16 + r16) * HS_LD + k0 + q * 8];  // q*8: LDS read needs explicit lane K-offset
            #pragma unroll
            for (int j = 0; j < 2; ++j) {
                const float* p = pb2[j] + ht * HT + k0;
                b8[j] = cvt8(*(const float4*)p, *(const float4*)(p + 4));
            }
            #pragma unroll
            for (int i = 0; i < 2; ++i)
                #pragma unroll
                for (int j = 0; j < 2; ++j)
                    acc2[i][j] = __builtin_amdgcn_mfma_f32_16x16x32_bf16(a8[i], b8[j], acc2[i][j], 0, 0, 0);
        }
    }

    // store out[b, o, c]; 16 c-writers of each 64B line share an XCD (swizzle)
    #pragma unroll
    for (int i = 0; i < 2; ++i)
        #pragma unroll
        for (int j = 0; j < 2; ++j)
            #pragma unroll
            for (int r = 0; r < 4; ++r) {
                const int bb = row0 + wm * 32 + i * 16 + q * 4 + r;
                const int o  = wn * 32 + j * 16 + r16;
                out[(size_t)bb * (Odim * Cdim) + o * Cdim + c] = acc2[i][j][r];
            }
}

extern "C" void kernel_launch(void* const* d_in, const int* in_sizes, int n_in,
                              void* d_out, int out_size, void* d_ws, size_t ws_size,
                              hipStream_t stream) {
    const float* x  = (const float*)d_in[0];
    const float* w1 = (const float*)d_in[1];
    const float* b1 = (const float*)d_in[2];
    const float* w2 = (const float*)d_in[3];
    const float* b2 = (const float*)d_in[4];
    float* out = (float*)d_out;
    mlp_fused2<<<dim3(512), dim3(512), 0, stream>>>(x, w1, b1, w2, b2, out);
}